// Round 7
// baseline (226.539 us; speedup 1.0000x reference)
//
#include <hip/hip_runtime.h>

// B=2, T=2048, C=1024, H=16, DQK=DV=64. Inputs fp32, output fp32, bf16 MFMA inside.

typedef short bf16x8 __attribute__((ext_vector_type(8)));
typedef float f32x4 __attribute__((ext_vector_type(4)));

#define MFMA_BF16 __builtin_amdgcn_mfma_f32_16x16x32_bf16

// log2(e)/8: Q pre-scale so softmax runs in base-2 domain (exp2 = bare v_exp_f32)
#define QSCALE 0.18033688011112042f

__device__ __forceinline__ unsigned short f2bf(float f) {
    union { float f; unsigned u; } un; un.f = f;
    unsigned r = un.u + 0x7fffu + ((un.u >> 16) & 1u);  // RNE
    return (unsigned short)(r >> 16);
}
__device__ __forceinline__ unsigned short f2bf_trunc(float f) {
    union { float f; unsigned u; } un; un.f = f;
    return (unsigned short)(un.u >> 16);
}
__device__ __forceinline__ unsigned pk2(float a, float b) {
    return (unsigned)f2bf(a) | ((unsigned)f2bf(b) << 16);
}
__device__ __forceinline__ void gload16(const void* g, void* l) {
    __builtin_amdgcn_global_load_lds(
        (const __attribute__((address_space(1))) unsigned int*)g,
        (__attribute__((address_space(3))) unsigned int*)l, 16, 0, 0);
}

// ---------- fused prep: x/wq/wk/wv fp32->bf16, wo fp32->bf16 transposed ----------
__global__ __launch_bounds__(256) void prep(
    const float* __restrict__ x, const float* __restrict__ wq,
    const float* __restrict__ wk, const float* __restrict__ wv,
    const float* __restrict__ wo,
    unsigned short* __restrict__ x16, unsigned short* __restrict__ wq16,
    unsigned short* __restrict__ wk16, unsigned short* __restrict__ wv16,
    unsigned short* __restrict__ wot)
{
    const int bid = blockIdx.x;
    if (bid < 3584) {
        const float* s; unsigned short* d; int off;
        if (bid < 2048)      { s = x;  d = x16;  off = bid * 2048; }
        else if (bid < 2560) { s = wq; d = wq16; off = (bid - 2048) * 2048; }
        else if (bid < 3072) { s = wk; d = wk16; off = (bid - 2560) * 2048; }
        else                 { s = wv; d = wv16; off = (bid - 3072) * 2048; }
        int i = off + threadIdx.x * 8;
        float4 f0 = *(const float4*)&s[i], f1 = *(const float4*)&s[i + 4];
        uint4 o;
        o.x = pk2(f0.x, f0.y); o.y = pk2(f0.z, f0.w);
        o.z = pk2(f1.x, f1.y); o.w = pk2(f1.z, f1.w);
        *(uint4*)&d[i] = o;
    } else {
        // wo [K=1024][N=1024] -> wot [N][K] bf16
        __shared__ unsigned short t[64 * 72];
        const int b2 = bid - 3584;
        const int k0 = (b2 & 15) << 6, n0 = (b2 >> 4) << 6;
        const int r = threadIdx.x >> 2, cg = (threadIdx.x & 3) << 4;
        const float* src = &wo[(k0 + r) * 1024 + n0 + cg];
        #pragma unroll
        for (int j = 0; j < 16; j += 4) {
            float4 f = *(const float4*)&src[j];
            t[(cg + j + 0) * 72 + r] = f2bf(f.x);
            t[(cg + j + 1) * 72 + r] = f2bf(f.y);
            t[(cg + j + 2) * 72 + r] = f2bf(f.z);
            t[(cg + j + 3) * 72 + r] = f2bf(f.w);
        }
        __syncthreads();
        unsigned short* dst = &wot[(n0 + r) * 1024 + k0 + cg];
        unsigned short* tr = &t[r * 72 + cg];
        unsigned v[16];
        #pragma unroll
        for (int j = 0; j < 16; ++j) v[j] = tr[j];
        uint4 o0, o1;
        o0.x = v[0] | (v[1] << 16);   o0.y = v[2] | (v[3] << 16);
        o0.z = v[4] | (v[5] << 16);   o0.w = v[6] | (v[7] << 16);
        o1.x = v[8] | (v[9] << 16);   o1.y = v[10] | (v[11] << 16);
        o1.z = v[12] | (v[13] << 16); o1.w = v[14] | (v[15] << 16);
        *(uint4*)&dst[0] = o0;
        *(uint4*)&dst[8] = o1;
    }
}

// ---------- shared 128x128 bf16 GEMM tile body, K=1024, lda=ldb=1024 ----------
__device__ __forceinline__ void gemm_body(
    const unsigned short* __restrict__ A, const unsigned short* __restrict__ Bm,
    void* __restrict__ C, int m0, int n0, int mode, int ldc, float sc)
{
    __shared__ unsigned short sa[128 * 64];
    __shared__ unsigned short sb[128 * 64];
    const int tid = threadIdx.x, wave = tid >> 6, lane = tid & 63;
    const int l15 = lane & 15, l4 = lane >> 4;
    const int wm = (wave >> 1) << 6, wn = (wave & 1) << 6;
    const int lrow = lane >> 3, lcb = (lane & 7) << 3;

    f32x4 acc[4][4] = {};

    for (int k0 = 0; k0 < 1024; k0 += 64) {
        #pragma unroll
        for (int i = 0; i < 4; ++i) {
            int rbase = i * 32 + wave * 8;
            gload16(&A[(size_t)(m0 + rbase + lrow) * 1024 + k0 + lcb], &sa[rbase * 64]);
            gload16(&Bm[(size_t)(n0 + rbase + lrow) * 1024 + k0 + lcb], &sb[rbase * 64]);
        }
        __syncthreads();
        #pragma unroll
        for (int ks = 0; ks < 2; ++ks) {
            bf16x8 af[4], bf[4];
            #pragma unroll
            for (int i = 0; i < 4; ++i)
                af[i] = *(const bf16x8*)&sa[(wm + i * 16 + l15) * 64 + ks * 32 + l4 * 8];
            #pragma unroll
            for (int j = 0; j < 4; ++j)
                bf[j] = *(const bf16x8*)&sb[(wn + j * 16 + l15) * 64 + ks * 32 + l4 * 8];
            #pragma unroll
            for (int i = 0; i < 4; ++i)
                #pragma unroll
                for (int j = 0; j < 4; ++j)
                    acc[i][j] = MFMA_BF16(af[i], bf[j], acc[i][j], 0, 0, 0);
        }
        __syncthreads();
    }

    #pragma unroll
    for (int i = 0; i < 4; ++i)
        #pragma unroll
        for (int j = 0; j < 4; ++j)
            #pragma unroll
            for (int r = 0; r < 4; ++r) {
                int row = m0 + wm + i * 16 + l4 * 4 + r;
                int col = n0 + wn + j * 16 + l15;
                float val = acc[i][j][r];
                if (mode == 0) {
                    int nb = row >> 11, t = row & 2047;
                    int hh = col >> 6, dd = col & 63;
                    ((unsigned short*)C)[(((nb << 4) + hh) * 2048 + t) * 64 + dd] =
                        f2bf(val * sc);
                } else if (mode == 1) {
                    ((float*)C)[(size_t)row * ldc + col] = val;
                } else {
                    ((unsigned short*)C)[(size_t)row * ldc + col] = f2bf(val);
                }
            }
}

// grid 768: [0,512) QK fused | [512,768) V^T = Wv @ X^T
__global__ __launch_bounds__(256) void proj(
    const unsigned short* __restrict__ x16,
    const unsigned short* __restrict__ wq16,
    const unsigned short* __restrict__ wk16,
    const unsigned short* __restrict__ wv16,
    unsigned short* __restrict__ qbuf,
    unsigned short* __restrict__ kbuf,
    unsigned short* __restrict__ vtb)
{
    const int bid = blockIdx.x;
    if (bid < 512) {
        int m0 = (bid & 31) << 7;
        int n0g = (bid >> 5) << 7;
        if (n0g < 1024)
            gemm_body(x16, wq16, qbuf, m0, n0g, 0, 0, QSCALE);
        else
            gemm_body(x16, wk16, kbuf, m0, n0g - 1024, 0, 0, 1.0f);
    } else {
        int v = bid - 512;
        gemm_body(wv16, x16, vtb, (v & 7) << 7, (v >> 3) << 7, 2, 4096, 1.0f);
    }
}

// ---------- out = Y @ Wo^T(stored [N][K]): 64x128 tiles, 512 blocks (2/CU) ----------
__global__ __launch_bounds__(256) void outp(
    const unsigned short* __restrict__ ybuf,
    const unsigned short* __restrict__ wot,
    float* __restrict__ out)
{
    __shared__ unsigned short sa[64 * 64];
    __shared__ unsigned short sb[128 * 64];
    const int tid = threadIdx.x, wave = tid >> 6, lane = tid & 63;
    const int l15 = lane & 15, l4 = lane >> 4;
    const int bid = blockIdx.x;
    const int m0 = (bid & 63) << 6, n0 = (bid >> 6) << 7;
    const int lrow = lane >> 3, lcb = (lane & 7) << 3;

    f32x4 acc[8] = {};

    for (int k0 = 0; k0 < 1024; k0 += 64) {
        #pragma unroll
        for (int i = 0; i < 2; ++i) {
            int rbase = i * 32 + wave * 8;
            gload16(&ybuf[(size_t)(m0 + rbase + lrow) * 1024 + k0 + lcb], &sa[rbase * 64]);
        }
        #pragma unroll
        for (int i = 0; i < 4; ++i) {
            int rbase = i * 32 + wave * 8;
            gload16(&wot[(size_t)(n0 + rbase + lrow) * 1024 + k0 + lcb], &sb[rbase * 64]);
        }
        __syncthreads();
        #pragma unroll
        for (int ks = 0; ks < 2; ++ks) {
            bf16x8 af = *(const bf16x8*)&sa[(wave * 16 + l15) * 64 + ks * 32 + l4 * 8];
            #pragma unroll
            for (int j = 0; j < 8; ++j) {
                bf16x8 bf = *(const bf16x8*)&sb[(j * 16 + l15) * 64 + ks * 32 + l4 * 8];
                acc[j] = MFMA_BF16(af, bf, acc[j], 0, 0, 0);
            }
        }
        __syncthreads();
    }

    #pragma unroll
    for (int j = 0; j < 8; ++j)
        #pragma unroll
        for (int r = 0; r < 4; ++r) {
            int row = m0 + wave * 16 + l4 * 4 + r;
            int col = n0 + j * 16 + l15;
            out[(size_t)row * 1024 + col] = acc[j][r];
        }
}

// ---------- flash causal attention, fixed-max softmax, 128-row Q blocks ----------
// q,k: [B,H,T,64] bf16 (q pre-scaled to log2 domain). vt: [H*64][B*T]. y: [B*T][1024].
// 512 blocks (2/CU); wave owns 32 q-rows (2 m-frags); kf/vf read once, feed both mi.
// sp XOR-swizzle (col ^= ((row>>3)&1)<<4) puts l4 row-groups on bank sets {0,16,8,24}
// -> removes the 4-way b16-write conflicts measured in R5/R6 (4.87e6).
// Balanced causal pairing: pairs {c, c+256} sum to 34 steps.
__global__ __launch_bounds__(256) void attn(
    const unsigned short* __restrict__ q,
    const unsigned short* __restrict__ k,
    const unsigned short* __restrict__ vt,
    unsigned short* __restrict__ y)
{
    constexpr int P = 72;
    __shared__ unsigned short sk[64 * P];
    __shared__ unsigned short sv[64 * P];    // [d][s]
    __shared__ unsigned short sp[128 * P];   // wave-private C->A layout round-trip
    const int tid = threadIdx.x, wave = tid >> 6, lane = tid & 63;
    const int l15 = lane & 15, l4 = lane >> 4;
    const int bid = blockIdx.x;
    const int qtt = (bid < 256) ? (15 - (bid >> 5)) : ((bid - 256) >> 5);
    const int bh = bid & 31;
    const int nb = bh >> 4, hh = bh & 15;
    const int q0 = qtt << 7;
    const size_t base = (size_t)bh << 17;

    // Q fragments straight from global (A-layout: m=l15, k=l4*8..+7), once per block
    bf16x8 qf[2][2];
    #pragma unroll
    for (int mi = 0; mi < 2; ++mi)
        #pragma unroll
        for (int ks = 0; ks < 2; ++ks)
            qf[mi][ks] = *(const bf16x8*)
                &q[base + (size_t)(q0 + wave * 32 + mi * 16 + l15) * 64 + ks * 32 + l4 * 8];

    float l_part[2][4] = {};
    f32x4 acc_o[2][4] = {};

    const int swW = (l4 >> 1) << 4;          // write swizzle: row bit3 = l4>>1
    const int swR = ((l15 >> 3) & 1) << 4;   // read swizzle: row bit3 = l15>>3

    const int nst = 2 * qtt + 2;
    for (int st = 0; st < nst; ++st) {
        const int s0 = st << 6;
        for (int vv = tid; vv < 512; vv += 256) {
            int row = vv >> 3, col = (vv & 7) << 3;
            *(uint4*)&sk[row * P + col] =
                *(const uint4*)&k[base + (size_t)((s0 + row) << 6) + col];
            *(uint4*)&sv[row * P + col] =
                *(const uint4*)&vt[(size_t)((hh << 6) + row) * 4096 + (nb << 11) + s0 + col];
        }
        __syncthreads();

        // S' = Q K^T in log2 domain; kf read once, feeds both mi
        f32x4 s_acc[2][4] = {};
        #pragma unroll
        for (int ks = 0; ks < 2; ++ks)
            #pragma unroll
            for (int ns = 0; ns < 4; ++ns) {
                bf16x8 kf = *(const bf16x8*)&sk[(ns * 16 + l15) * P + ks * 32 + l4 * 8];
                s_acc[0][ns] = MFMA_BF16(qf[0][ks], kf, s_acc[0][ns], 0, 0, 0);
                s_acc[1][ns] = MFMA_BF16(qf[1][ks], kf, s_acc[1][ns], 0, 0, 0);
            }

        // causal mask on the two diagonal steps (uniform branch)
        if (st >= 2 * qtt) {
            const int soff = (st - 2 * qtt) << 6;
            #pragma unroll
            for (int mi = 0; mi < 2; ++mi) {
                const int rb = wave * 32 + mi * 16 + l4 * 4;
                #pragma unroll
                for (int ns = 0; ns < 4; ++ns) {
                    const int cl = soff + ns * 16 + l15;
                    #pragma unroll
                    for (int r = 0; r < 4; ++r)
                        if (cl > rb + r) s_acc[mi][ns][r] = -1e30f;
                }
            }
        }

        // P = exp2(S'), pack bf16 to LDS (swizzled A-layout rows), deferred row-sum
        #pragma unroll
        for (int mi = 0; mi < 2; ++mi)
            #pragma unroll
            for (int r = 0; r < 4; ++r) {
                float p0 = exp2f(s_acc[mi][0][r]);
                float p1 = exp2f(s_acc[mi][1][r]);
                float p2 = exp2f(s_acc[mi][2][r]);
                float p3 = exp2f(s_acc[mi][3][r]);
                const int rowl = (wave * 32 + mi * 16 + l4 * 4 + r) * P;
                sp[rowl + (( 0 + l15) ^ swW)] = f2bf_trunc(p0);
                sp[rowl + ((16 + l15) ^ swW)] = f2bf_trunc(p1);
                sp[rowl + ((32 + l15) ^ swW)] = f2bf_trunc(p2);
                sp[rowl + ((48 + l15) ^ swW)] = f2bf_trunc(p3);
                l_part[mi][r] += (p0 + p1) + (p2 + p3);
            }

        // O += P V; sp is wave-private (same-wave DS ordered) -> no barrier before reads
        #pragma unroll
        for (int ks = 0; ks < 2; ++ks) {
            bf16x8 pf0 = *(const bf16x8*)
                &sp[(wave * 32 + l15) * P + ((ks * 32 + l4 * 8) ^ swR)];
            bf16x8 pf1 = *(const bf16x8*)
                &sp[(wave * 32 + 16 + l15) * P + ((ks * 32 + l4 * 8) ^ swR)];
            #pragma unroll
            for (int ds = 0; ds < 4; ++ds) {
                bf16x8 vf = *(const bf16x8*)&sv[(ds * 16 + l15) * P + ks * 32 + l4 * 8];
                acc_o[0][ds] = MFMA_BF16(pf0, vf, acc_o[0][ds], 0, 0, 0);
                acc_o[1][ds] = MFMA_BF16(pf1, vf, acc_o[1][ds], 0, 0, 0);
            }
        }
        __syncthreads();  // before next tile's staging overwrites sk/sv
    }

    #pragma unroll
    for (int mi = 0; mi < 2; ++mi) {
        float rl[4];
        #pragma unroll
        for (int r = 0; r < 4; ++r) {
            float s = l_part[mi][r];
            #pragma unroll
            for (int off = 1; off < 16; off <<= 1) s += __shfl_xor(s, off);
            rl[r] = __builtin_amdgcn_rcpf(s);
        }
        #pragma unroll
        for (int ds = 0; ds < 4; ++ds)
            #pragma unroll
            for (int r = 0; r < 4; ++r) {
                const int rg = q0 + wave * 32 + mi * 16 + l4 * 4 + r;
                y[((size_t)((nb << 11) + rg) << 10) + (hh << 6) + ds * 16 + l15] =
                    f2bf(acc_o[mi][ds][r] * rl[r]);
            }
    }
}

extern "C" void kernel_launch(void* const* d_in, const int* in_sizes, int n_in,
                              void* d_out, int out_size, void* d_ws, size_t ws_size,
                              hipStream_t stream) {
    const float* x  = (const float*)d_in[0];
    const float* wq = (const float*)d_in[1];
    const float* wk = (const float*)d_in[2];
    const float* wv = (const float*)d_in[3];
    const float* wo = (const float*)d_in[4];
    float* out = (float*)d_out;

    const size_t M1 = 1u << 20;
    unsigned short* x16  = (unsigned short*)d_ws;          // 4M
    unsigned short* wq16 = x16 + 4 * M1;                   // 1M
    unsigned short* wk16 = wq16 + M1;
    unsigned short* wv16 = wk16 + M1;
    unsigned short* wot  = wv16 + M1;                      // 1M
    unsigned short* qbuf = wot + M1;                       // 4M [B,H,T,64]
    unsigned short* kbuf = qbuf + 4 * M1;                  // 4M
    unsigned short* vtb  = kbuf + 4 * M1;                  // 4M [1024][4096]
    unsigned short* ybuf = vtb + 4 * M1;                   // 4M [4096][1024]

    dim3 blk(256);
    prep<<<3840, blk, 0, stream>>>(x, wq, wk, wv, wo, x16, wq16, wk16, wv16, wot);
    proj<<<768, blk, 0, stream>>>(x16, wq16, wk16, wv16, qbuf, kbuf, vtb);
    attn<<<512, blk, 0, stream>>>(qbuf, kbuf, vtb, ybuf);
    outp<<<512, blk, 0, stream>>>(ybuf, wot, out);
}

// Round 8
// 215.676 us; speedup vs baseline: 1.0504x; 1.0504x over previous
//
#include <hip/hip_runtime.h>

// B=2, T=2048, C=1024, H=16, DQK=DV=64. Inputs fp32, output fp32, bf16 MFMA inside.

typedef short bf16x8 __attribute__((ext_vector_type(8)));
typedef float f32x4 __attribute__((ext_vector_type(4)));

#define MFMA_BF16 __builtin_amdgcn_mfma_f32_16x16x32_bf16

// log2(e)/8: Q pre-scale so softmax runs in base-2 domain (exp2 = bare v_exp_f32)
#define QSCALE 0.18033688011112042f

__device__ __forceinline__ unsigned short f2bf(float f) {
    union { float f; unsigned u; } un; un.f = f;
    unsigned r = un.u + 0x7fffu + ((un.u >> 16) & 1u);  // RNE
    return (unsigned short)(r >> 16);
}
__device__ __forceinline__ unsigned short f2bf_trunc(float f) {
    union { float f; unsigned u; } un; un.f = f;
    return (unsigned short)(un.u >> 16);
}
__device__ __forceinline__ unsigned pk2(float a, float b) {
    return (unsigned)f2bf(a) | ((unsigned)f2bf(b) << 16);
}
__device__ __forceinline__ void gload16(const void* g, void* l) {
    __builtin_amdgcn_global_load_lds(
        (const __attribute__((address_space(1))) unsigned int*)g,
        (__attribute__((address_space(3))) unsigned int*)l, 16, 0, 0);
}

// ---------- fused prep: x/wq/wk/wv fp32->bf16, wo fp32->bf16 transposed ----------
__global__ __launch_bounds__(256) void prep(
    const float* __restrict__ x, const float* __restrict__ wq,
    const float* __restrict__ wk, const float* __restrict__ wv,
    const float* __restrict__ wo,
    unsigned short* __restrict__ x16, unsigned short* __restrict__ wq16,
    unsigned short* __restrict__ wk16, unsigned short* __restrict__ wv16,
    unsigned short* __restrict__ wot)
{
    const int bid = blockIdx.x;
    if (bid < 3584) {
        const float* s; unsigned short* d; int off;
        if (bid < 2048)      { s = x;  d = x16;  off = bid * 2048; }
        else if (bid < 2560) { s = wq; d = wq16; off = (bid - 2048) * 2048; }
        else if (bid < 3072) { s = wk; d = wk16; off = (bid - 2560) * 2048; }
        else                 { s = wv; d = wv16; off = (bid - 3072) * 2048; }
        int i = off + threadIdx.x * 8;
        float4 f0 = *(const float4*)&s[i], f1 = *(const float4*)&s[i + 4];
        uint4 o;
        o.x = pk2(f0.x, f0.y); o.y = pk2(f0.z, f0.w);
        o.z = pk2(f1.x, f1.y); o.w = pk2(f1.z, f1.w);
        *(uint4*)&d[i] = o;
    } else {
        // wo [K=1024][N=1024] -> wot [N][K] bf16
        __shared__ unsigned short t[64 * 72];
        const int b2 = bid - 3584;
        const int k0 = (b2 & 15) << 6, n0 = (b2 >> 4) << 6;
        const int r = threadIdx.x >> 2, cg = (threadIdx.x & 3) << 4;
        const float* src = &wo[(k0 + r) * 1024 + n0 + cg];
        #pragma unroll
        for (int j = 0; j < 16; j += 4) {
            float4 f = *(const float4*)&src[j];
            t[(cg + j + 0) * 72 + r] = f2bf(f.x);
            t[(cg + j + 1) * 72 + r] = f2bf(f.y);
            t[(cg + j + 2) * 72 + r] = f2bf(f.z);
            t[(cg + j + 3) * 72 + r] = f2bf(f.w);
        }
        __syncthreads();
        unsigned short* dst = &wot[(n0 + r) * 1024 + k0 + cg];
        unsigned short* tr = &t[r * 72 + cg];
        unsigned v[16];
        #pragma unroll
        for (int j = 0; j < 16; ++j) v[j] = tr[j];
        uint4 o0, o1;
        o0.x = v[0] | (v[1] << 16);   o0.y = v[2] | (v[3] << 16);
        o0.z = v[4] | (v[5] << 16);   o0.w = v[6] | (v[7] << 16);
        o1.x = v[8] | (v[9] << 16);   o1.y = v[10] | (v[11] << 16);
        o1.z = v[12] | (v[13] << 16); o1.w = v[14] | (v[15] << 16);
        *(uint4*)&dst[0] = o0;
        *(uint4*)&dst[8] = o1;
    }
}

// ---------- shared 128x128 bf16 GEMM tile body, K=1024, lda=ldb=1024 ----------
__device__ __forceinline__ void gemm_body(
    const unsigned short* __restrict__ A, const unsigned short* __restrict__ Bm,
    void* __restrict__ C, int m0, int n0, int mode, int ldc, float sc)
{
    __shared__ unsigned short sa[128 * 64];
    __shared__ unsigned short sb[128 * 64];
    const int tid = threadIdx.x, wave = tid >> 6, lane = tid & 63;
    const int l15 = lane & 15, l4 = lane >> 4;
    const int wm = (wave >> 1) << 6, wn = (wave & 1) << 6;
    const int lrow = lane >> 3, lcb = (lane & 7) << 3;

    f32x4 acc[4][4] = {};

    for (int k0 = 0; k0 < 1024; k0 += 64) {
        #pragma unroll
        for (int i = 0; i < 4; ++i) {
            int rbase = i * 32 + wave * 8;
            gload16(&A[(size_t)(m0 + rbase + lrow) * 1024 + k0 + lcb], &sa[rbase * 64]);
            gload16(&Bm[(size_t)(n0 + rbase + lrow) * 1024 + k0 + lcb], &sb[rbase * 64]);
        }
        __syncthreads();
        #pragma unroll
        for (int ks = 0; ks < 2; ++ks) {
            bf16x8 af[4], bf[4];
            #pragma unroll
            for (int i = 0; i < 4; ++i)
                af[i] = *(const bf16x8*)&sa[(wm + i * 16 + l15) * 64 + ks * 32 + l4 * 8];
            #pragma unroll
            for (int j = 0; j < 4; ++j)
                bf[j] = *(const bf16x8*)&sb[(wn + j * 16 + l15) * 64 + ks * 32 + l4 * 8];
            #pragma unroll
            for (int i = 0; i < 4; ++i)
                #pragma unroll
                for (int j = 0; j < 4; ++j)
                    acc[i][j] = MFMA_BF16(af[i], bf[j], acc[i][j], 0, 0, 0);
        }
        __syncthreads();
    }

    #pragma unroll
    for (int i = 0; i < 4; ++i)
        #pragma unroll
        for (int j = 0; j < 4; ++j)
            #pragma unroll
            for (int r = 0; r < 4; ++r) {
                int row = m0 + wm + i * 16 + l4 * 4 + r;
                int col = n0 + wn + j * 16 + l15;
                float val = acc[i][j][r];
                if (mode == 0) {
                    int nb = row >> 11, t = row & 2047;
                    int hh = col >> 6, dd = col & 63;
                    ((unsigned short*)C)[(((nb << 4) + hh) * 2048 + t) * 64 + dd] =
                        f2bf(val * sc);
                } else if (mode == 1) {
                    ((float*)C)[(size_t)row * ldc + col] = val;
                } else {
                    ((unsigned short*)C)[(size_t)row * ldc + col] = f2bf(val);
                }
            }
}

// grid 768: [0,512) QK fused | [512,768) V^T = Wv @ X^T
__global__ __launch_bounds__(256) void proj(
    const unsigned short* __restrict__ x16,
    const unsigned short* __restrict__ wq16,
    const unsigned short* __restrict__ wk16,
    const unsigned short* __restrict__ wv16,
    unsigned short* __restrict__ qbuf,
    unsigned short* __restrict__ kbuf,
    unsigned short* __restrict__ vtb)
{
    const int bid = blockIdx.x;
    if (bid < 512) {
        int m0 = (bid & 31) << 7;
        int n0g = (bid >> 5) << 7;
        if (n0g < 1024)
            gemm_body(x16, wq16, qbuf, m0, n0g, 0, 0, QSCALE);
        else
            gemm_body(x16, wk16, kbuf, m0, n0g - 1024, 0, 0, 1.0f);
    } else {
        int v = bid - 512;
        gemm_body(wv16, x16, vtb, (v & 7) << 7, (v >> 3) << 7, 2, 4096, 1.0f);
    }
}

// ---------- out = Y @ Wo^T(stored [N][K]): 64x128 tiles, 512 blocks (2/CU) ----------
__global__ __launch_bounds__(256) void outp(
    const unsigned short* __restrict__ ybuf,
    const unsigned short* __restrict__ wot,
    float* __restrict__ out)
{
    __shared__ unsigned short sa[64 * 64];
    __shared__ unsigned short sb[128 * 64];
    const int tid = threadIdx.x, wave = tid >> 6, lane = tid & 63;
    const int l15 = lane & 15, l4 = lane >> 4;
    const int bid = blockIdx.x;
    const int m0 = (bid & 63) << 6, n0 = (bid >> 6) << 7;
    const int lrow = lane >> 3, lcb = (lane & 7) << 3;

    f32x4 acc[8] = {};

    for (int k0 = 0; k0 < 1024; k0 += 64) {
        #pragma unroll
        for (int i = 0; i < 2; ++i) {
            int rbase = i * 32 + wave * 8;
            gload16(&ybuf[(size_t)(m0 + rbase + lrow) * 1024 + k0 + lcb], &sa[rbase * 64]);
        }
        #pragma unroll
        for (int i = 0; i < 4; ++i) {
            int rbase = i * 32 + wave * 8;
            gload16(&wot[(size_t)(n0 + rbase + lrow) * 1024 + k0 + lcb], &sb[rbase * 64]);
        }
        __syncthreads();
        #pragma unroll
        for (int ks = 0; ks < 2; ++ks) {
            bf16x8 af = *(const bf16x8*)&sa[(wave * 16 + l15) * 64 + ks * 32 + l4 * 8];
            #pragma unroll
            for (int j = 0; j < 8; ++j) {
                bf16x8 bf = *(const bf16x8*)&sb[(j * 16 + l15) * 64 + ks * 32 + l4 * 8];
                acc[j] = MFMA_BF16(af, bf, acc[j], 0, 0, 0);
            }
        }
        __syncthreads();
    }

    #pragma unroll
    for (int j = 0; j < 8; ++j)
        #pragma unroll
        for (int r = 0; r < 4; ++r) {
            int row = m0 + wave * 16 + l4 * 4 + r;
            int col = n0 + j * 16 + l15;
            out[(size_t)row * 1024 + col] = acc[j][r];
        }
}

// ---------- flash causal attention, fixed-max softmax (R6 structure + sp swizzle) ----------
// q,k: [B,H,T,64] bf16 (q pre-scaled to log2 domain). vt: [H*64][B*T]. y: [B*T][1024].
// 64 q-rows per block (1024 blocks -> 4 blocks/CU; R7 showed 128-row/2-per-CU loses:
// the MFMA->exp2->pack->MFMA chain needs cross-block overlap). Wave owns 16 rows.
// sp XOR swizzle: col bit4 ^= row bit3 (write (l4&2)<<3, read (l15&8)<<1) — breaks the
// 4-way b16-write aliasing; measured -96 conflict-cyc/step in R7.
// Balanced causal pairing: co-resident {c,c+256,c+512,c+768} sum to 62 steps.
__global__ __launch_bounds__(256) void attn(
    const unsigned short* __restrict__ q,
    const unsigned short* __restrict__ k,
    const unsigned short* __restrict__ vt,
    unsigned short* __restrict__ y)
{
    constexpr int P = 72;
    __shared__ unsigned short sk[64 * P];
    __shared__ unsigned short sv[64 * P];   // [d][s]
    __shared__ unsigned short sp[64 * P];   // wave-private C->A layout round-trip
    const int tid = threadIdx.x, wave = tid >> 6, lane = tid & 63;
    const int l15 = lane & 15, l4 = lane >> 4;
    const int bid = blockIdx.x;
    const int qtt = (bid < 512) ? (31 - (bid >> 5)) : ((bid - 512) >> 5);
    const int bh = bid & 31;
    const int nb = bh >> 4, hh = bh & 15;
    const int q0 = qtt << 6;
    const size_t base = (size_t)bh << 17;

    // Q fragments straight from global (A-layout: m=l15, k=l4*8..+7), once per block
    bf16x8 qf[2];
    #pragma unroll
    for (int ks = 0; ks < 2; ++ks)
        qf[ks] = *(const bf16x8*)
            &q[base + (size_t)(q0 + wave * 16 + l15) * 64 + ks * 32 + l4 * 8];

    float l_part[4] = {0.f, 0.f, 0.f, 0.f};
    f32x4 acc_o[4] = {};

    const int swW = (l4 & 2) << 3;      // write: row bit3 = (l4*4+r)>>3 = l4>>1
    const int swR = (l15 & 8) << 1;     // read: row bit3 = l15>>3

    const int nst = qtt + 1;
    for (int st = 0; st < nst; ++st) {
        const int s0 = st << 6;
        for (int vv = tid; vv < 512; vv += 256) {
            int row = vv >> 3, col = (vv & 7) << 3;
            *(uint4*)&sk[row * P + col] =
                *(const uint4*)&k[base + (size_t)((s0 + row) << 6) + col];
            *(uint4*)&sv[row * P + col] =
                *(const uint4*)&vt[(size_t)((hh << 6) + row) * 4096 + (nb << 11) + s0 + col];
        }
        __syncthreads();

        // S' = Q K^T in log2 domain
        f32x4 s_acc[4] = {};
        #pragma unroll
        for (int ks = 0; ks < 2; ++ks)
            #pragma unroll
            for (int ns = 0; ns < 4; ++ns) {
                bf16x8 kf = *(const bf16x8*)&sk[(ns * 16 + l15) * P + ks * 32 + l4 * 8];
                s_acc[ns] = MFMA_BF16(qf[ks], kf, s_acc[ns], 0, 0, 0);
            }

        // causal mask only on the diagonal step (uniform branch)
        if (st == qtt) {
            #pragma unroll
            for (int ns = 0; ns < 4; ++ns) {
                const int cl = ns * 16 + l15;          // column - s0
                #pragma unroll
                for (int r = 0; r < 4; ++r) {
                    const int rl = wave * 16 + l4 * 4 + r;  // row - q0 (s0 == q0 here)
                    if (cl > rl) s_acc[ns][r] = -1e30f;
                }
            }
        }

        // P = exp2(S'), pack to bf16 in LDS (swizzled A-layout rows), deferred row-sum
        #pragma unroll
        for (int r = 0; r < 4; ++r) {
            float p0 = exp2f(s_acc[0][r]);
            float p1 = exp2f(s_acc[1][r]);
            float p2 = exp2f(s_acc[2][r]);
            float p3 = exp2f(s_acc[3][r]);
            const int rowl = (wave * 16 + l4 * 4 + r) * P;
            sp[rowl + (( 0 + l15) ^ swW)] = f2bf_trunc(p0);
            sp[rowl + ((16 + l15) ^ swW)] = f2bf_trunc(p1);
            sp[rowl + ((32 + l15) ^ swW)] = f2bf_trunc(p2);
            sp[rowl + ((48 + l15) ^ swW)] = f2bf_trunc(p3);
            l_part[r] += (p0 + p1) + (p2 + p3);
        }

        // O += P V; sp is wave-private (same-wave DS ordered) -> no barrier before reads
        #pragma unroll
        for (int ks = 0; ks < 2; ++ks) {
            bf16x8 pf = *(const bf16x8*)
                &sp[(wave * 16 + l15) * P + ((ks * 32 + l4 * 8) ^ swR)];
            #pragma unroll
            for (int ds = 0; ds < 4; ++ds) {
                bf16x8 vf = *(const bf16x8*)&sv[(ds * 16 + l15) * P + ks * 32 + l4 * 8];
                acc_o[ds] = MFMA_BF16(pf, vf, acc_o[ds], 0, 0, 0);
            }
        }
        __syncthreads();  // before next tile's staging overwrites sk/sv
    }

    // one-time l reduce across the 16-lane row group, then O/l
    float rl[4];
    #pragma unroll
    for (int r = 0; r < 4; ++r) {
        float s = l_part[r];
        #pragma unroll
        for (int off = 1; off < 16; off <<= 1) s += __shfl_xor(s, off);
        rl[r] = __builtin_amdgcn_rcpf(s);
    }
    #pragma unroll
    for (int ds = 0; ds < 4; ++ds)
        #pragma unroll
        for (int r = 0; r < 4; ++r) {
            const int rg = q0 + wave * 16 + l4 * 4 + r;
            y[((size_t)((nb << 11) + rg) << 10) + (hh << 6) + ds * 16 + l15] =
                f2bf(acc_o[ds][r] * rl[r]);
        }
}

extern "C" void kernel_launch(void* const* d_in, const int* in_sizes, int n_in,
                              void* d_out, int out_size, void* d_ws, size_t ws_size,
                              hipStream_t stream) {
    const float* x  = (const float*)d_in[0];
    const float* wq = (const float*)d_in[1];
    const float* wk = (const float*)d_in[2];
    const float* wv = (const float*)d_in[3];
    const float* wo = (const float*)d_in[4];
    float* out = (float*)d_out;

    const size_t M1 = 1u << 20;
    unsigned short* x16  = (unsigned short*)d_ws;          // 4M
    unsigned short* wq16 = x16 + 4 * M1;                   // 1M
    unsigned short* wk16 = wq16 + M1;
    unsigned short* wv16 = wk16 + M1;
    unsigned short* wot  = wv16 + M1;                      // 1M
    unsigned short* qbuf = wot + M1;                       // 4M [B,H,T,64]
    unsigned short* kbuf = qbuf + 4 * M1;                  // 4M
    unsigned short* vtb  = kbuf + 4 * M1;                  // 4M [1024][4096]
    unsigned short* ybuf = vtb + 4 * M1;                   // 4M [4096][1024]

    dim3 blk(256);
    prep<<<3840, blk, 0, stream>>>(x, wq, wk, wv, wo, x16, wq16, wk16, wv16, wot);
    proj<<<768, blk, 0, stream>>>(x16, wq16, wk16, wv16, qbuf, kbuf, vtb);
    attn<<<1024, blk, 0, stream>>>(qbuf, kbuf, vtb, ybuf);
    outp<<<512, blk, 0, stream>>>(ybuf, wot, out);
}

// Round 9
// 210.373 us; speedup vs baseline: 1.0768x; 1.0252x over previous
//
#include <hip/hip_runtime.h>

// B=2, T=2048, C=1024, H=16, DQK=DV=64. Inputs fp32, output fp32, bf16 MFMA inside.

typedef short bf16x4 __attribute__((ext_vector_type(4)));
typedef short bf16x8 __attribute__((ext_vector_type(8)));
typedef float f32x4 __attribute__((ext_vector_type(4)));

#define MFMA_BF16 __builtin_amdgcn_mfma_f32_16x16x32_bf16

// log2(e)/8: Q pre-scale so softmax runs in base-2 domain (exp2 = bare v_exp_f32)
#define QSCALE 0.18033688011112042f

__device__ __forceinline__ unsigned short f2bf(float f) {
    union { float f; unsigned u; } un; un.f = f;
    unsigned r = un.u + 0x7fffu + ((un.u >> 16) & 1u);  // RNE
    return (unsigned short)(r >> 16);
}
__device__ __forceinline__ unsigned pk2(float a, float b) {
    return (unsigned)f2bf(a) | ((unsigned)f2bf(b) << 16);
}
// truncating pack of two floats into packed bf16x2 (1-2 VALU ops)
__device__ __forceinline__ unsigned pk2t(float a, float b) {
    union { float f; unsigned u; } ua, ub; ua.f = a; ub.f = b;
    return (ua.u >> 16) | (ub.u & 0xffff0000u);
}
__device__ __forceinline__ void gload16(const void* g, void* l) {
    __builtin_amdgcn_global_load_lds(
        (const __attribute__((address_space(1))) unsigned int*)g,
        (__attribute__((address_space(3))) unsigned int*)l, 16, 0, 0);
}

// ---------- fused prep: x/wq/wk/wv fp32->bf16, wo fp32->bf16 transposed ----------
__global__ __launch_bounds__(256) void prep(
    const float* __restrict__ x, const float* __restrict__ wq,
    const float* __restrict__ wk, const float* __restrict__ wv,
    const float* __restrict__ wo,
    unsigned short* __restrict__ x16, unsigned short* __restrict__ wq16,
    unsigned short* __restrict__ wk16, unsigned short* __restrict__ wv16,
    unsigned short* __restrict__ wot)
{
    const int bid = blockIdx.x;
    if (bid < 3584) {
        const float* s; unsigned short* d; int off;
        if (bid < 2048)      { s = x;  d = x16;  off = bid * 2048; }
        else if (bid < 2560) { s = wq; d = wq16; off = (bid - 2048) * 2048; }
        else if (bid < 3072) { s = wk; d = wk16; off = (bid - 2560) * 2048; }
        else                 { s = wv; d = wv16; off = (bid - 3072) * 2048; }
        int i = off + threadIdx.x * 8;
        float4 f0 = *(const float4*)&s[i], f1 = *(const float4*)&s[i + 4];
        uint4 o;
        o.x = pk2(f0.x, f0.y); o.y = pk2(f0.z, f0.w);
        o.z = pk2(f1.x, f1.y); o.w = pk2(f1.z, f1.w);
        *(uint4*)&d[i] = o;
    } else {
        // wo [K=1024][N=1024] -> wot [N][K] bf16
        __shared__ unsigned short t[64 * 72];
        const int b2 = bid - 3584;
        const int k0 = (b2 & 15) << 6, n0 = (b2 >> 4) << 6;
        const int r = threadIdx.x >> 2, cg = (threadIdx.x & 3) << 4;
        const float* src = &wo[(k0 + r) * 1024 + n0 + cg];
        #pragma unroll
        for (int j = 0; j < 16; j += 4) {
            float4 f = *(const float4*)&src[j];
            t[(cg + j + 0) * 72 + r] = f2bf(f.x);
            t[(cg + j + 1) * 72 + r] = f2bf(f.y);
            t[(cg + j + 2) * 72 + r] = f2bf(f.z);
            t[(cg + j + 3) * 72 + r] = f2bf(f.w);
        }
        __syncthreads();
        unsigned short* dst = &wot[(n0 + r) * 1024 + k0 + cg];
        unsigned short* tr = &t[r * 72 + cg];
        unsigned v[16];
        #pragma unroll
        for (int j = 0; j < 16; ++j) v[j] = tr[j];
        uint4 o0, o1;
        o0.x = v[0] | (v[1] << 16);   o0.y = v[2] | (v[3] << 16);
        o0.z = v[4] | (v[5] << 16);   o0.w = v[6] | (v[7] << 16);
        o1.x = v[8] | (v[9] << 16);   o1.y = v[10] | (v[11] << 16);
        o1.z = v[12] | (v[13] << 16); o1.w = v[14] | (v[15] << 16);
        *(uint4*)&dst[0] = o0;
        *(uint4*)&dst[8] = o1;
    }
}

// ---------- shared 128x128 bf16 GEMM tile body, K=1024, lda=ldb=1024 ----------
__device__ __forceinline__ void gemm_body(
    const unsigned short* __restrict__ A, const unsigned short* __restrict__ Bm,
    void* __restrict__ C, int m0, int n0, int mode, int ldc, float sc)
{
    __shared__ unsigned short sa[128 * 64];
    __shared__ unsigned short sb[128 * 64];
    const int tid = threadIdx.x, wave = tid >> 6, lane = tid & 63;
    const int l15 = lane & 15, l4 = lane >> 4;
    const int wm = (wave >> 1) << 6, wn = (wave & 1) << 6;
    const int lrow = lane >> 3, lcb = (lane & 7) << 3;

    f32x4 acc[4][4] = {};

    for (int k0 = 0; k0 < 1024; k0 += 64) {
        #pragma unroll
        for (int i = 0; i < 4; ++i) {
            int rbase = i * 32 + wave * 8;
            gload16(&A[(size_t)(m0 + rbase + lrow) * 1024 + k0 + lcb], &sa[rbase * 64]);
            gload16(&Bm[(size_t)(n0 + rbase + lrow) * 1024 + k0 + lcb], &sb[rbase * 64]);
        }
        __syncthreads();
        #pragma unroll
        for (int ks = 0; ks < 2; ++ks) {
            bf16x8 af[4], bf[4];
            #pragma unroll
            for (int i = 0; i < 4; ++i)
                af[i] = *(const bf16x8*)&sa[(wm + i * 16 + l15) * 64 + ks * 32 + l4 * 8];
            #pragma unroll
            for (int j = 0; j < 4; ++j)
                bf[j] = *(const bf16x8*)&sb[(wn + j * 16 + l15) * 64 + ks * 32 + l4 * 8];
            #pragma unroll
            for (int i = 0; i < 4; ++i)
                #pragma unroll
                for (int j = 0; j < 4; ++j)
                    acc[i][j] = MFMA_BF16(af[i], bf[j], acc[i][j], 0, 0, 0);
        }
        __syncthreads();
    }

    #pragma unroll
    for (int i = 0; i < 4; ++i)
        #pragma unroll
        for (int j = 0; j < 4; ++j)
            #pragma unroll
            for (int r = 0; r < 4; ++r) {
                int row = m0 + wm + i * 16 + l4 * 4 + r;
                int col = n0 + wn + j * 16 + l15;
                float val = acc[i][j][r];
                if (mode == 0) {
                    int nb = row >> 11, t = row & 2047;
                    int hh = col >> 6, dd = col & 63;
                    ((unsigned short*)C)[(((nb << 4) + hh) * 2048 + t) * 64 + dd] =
                        f2bf(val * sc);
                } else if (mode == 1) {
                    ((float*)C)[(size_t)row * ldc + col] = val;
                } else {
                    ((unsigned short*)C)[(size_t)row * ldc + col] = f2bf(val);
                }
            }
}

// grid 768: [0,512) QK fused | [512,768) V^T = Wv @ X^T
__global__ __launch_bounds__(256) void proj(
    const unsigned short* __restrict__ x16,
    const unsigned short* __restrict__ wq16,
    const unsigned short* __restrict__ wk16,
    const unsigned short* __restrict__ wv16,
    unsigned short* __restrict__ qbuf,
    unsigned short* __restrict__ kbuf,
    unsigned short* __restrict__ vtb)
{
    const int bid = blockIdx.x;
    if (bid < 512) {
        int m0 = (bid & 31) << 7;
        int n0g = (bid >> 5) << 7;
        if (n0g < 1024)
            gemm_body(x16, wq16, qbuf, m0, n0g, 0, 0, QSCALE);
        else
            gemm_body(x16, wk16, kbuf, m0, n0g - 1024, 0, 0, 1.0f);
    } else {
        int v = bid - 512;
        gemm_body(wv16, x16, vtb, (v & 7) << 7, (v >> 3) << 7, 2, 4096, 1.0f);
    }
}

// ---------- out = Y @ Wo^T(stored [N][K]): 64x128 tiles, 512 blocks (2/CU) ----------
__global__ __launch_bounds__(256) void outp(
    const unsigned short* __restrict__ ybuf,
    const unsigned short* __restrict__ wot,
    float* __restrict__ out)
{
    __shared__ unsigned short sa[64 * 64];
    __shared__ unsigned short sb[128 * 64];
    const int tid = threadIdx.x, wave = tid >> 6, lane = tid & 63;
    const int l15 = lane & 15, l4 = lane >> 4;
    const int bid = blockIdx.x;
    const int m0 = (bid & 63) << 6, n0 = (bid >> 6) << 7;
    const int lrow = lane >> 3, lcb = (lane & 7) << 3;

    f32x4 acc[8] = {};

    for (int k0 = 0; k0 < 1024; k0 += 64) {
        #pragma unroll
        for (int i = 0; i < 2; ++i) {
            int rbase = i * 32 + wave * 8;
            gload16(&ybuf[(size_t)(m0 + rbase + lrow) * 1024 + k0 + lcb], &sa[rbase * 64]);
        }
        #pragma unroll
        for (int i = 0; i < 4; ++i) {
            int rbase = i * 32 + wave * 8;
            gload16(&wot[(size_t)(n0 + rbase + lrow) * 1024 + k0 + lcb], &sb[rbase * 64]);
        }
        __syncthreads();
        #pragma unroll
        for (int ks = 0; ks < 2; ++ks) {
            bf16x8 af = *(const bf16x8*)&sa[(wave * 16 + l15) * 64 + ks * 32 + l4 * 8];
            #pragma unroll
            for (int j = 0; j < 8; ++j) {
                bf16x8 bf = *(const bf16x8*)&sb[(j * 16 + l15) * 64 + ks * 32 + l4 * 8];
                acc[j] = MFMA_BF16(af, bf, acc[j], 0, 0, 0);
            }
        }
        __syncthreads();
    }

    #pragma unroll
    for (int j = 0; j < 8; ++j)
        #pragma unroll
        for (int r = 0; r < 4; ++r) {
            int row = m0 + wave * 16 + l4 * 4 + r;
            int col = n0 + j * 16 + l15;
            out[(size_t)row * 1024 + col] = acc[j][r];
        }
}

// ---------- flash causal attention: S^T formulation, P stays in registers ----------
// q,k: [B,H,T,64] bf16 (q pre-scaled to log2 domain). vt: [H*64][B*T]. y: [B*T][1024].
// Compute S^T = K Q^T (A=kf, B=qf; A/B lane layouts are identical). C-layout of S^T:
// [s=l4*4+r][q=l15]. With k-slot bijection sigma(ks,l4,j)=32ks+(j>>2)*16+l4*4+(j&3),
// exp2(s_acc) registers ARE the PV B-fragment (n=q,k=s) — zero cross-lane movement.
// A-operand V^T reads its k-slots through the same sigma: two b64 LDS reads/frag.
// O accumulates transposed [d][q]; epilogue packs 4 consecutive d per b64 store.
// Eliminates the sp array entirely (R6/R8's 288-320 conflict-cyc/step source).
// 64 q-rows/block, 1024 blocks (4/CU); balanced causal pairing (62 steps/CU-set).
__global__ __launch_bounds__(256) void attn(
    const unsigned short* __restrict__ q,
    const unsigned short* __restrict__ k,
    const unsigned short* __restrict__ vt,
    unsigned short* __restrict__ y)
{
    constexpr int P = 72;
    __shared__ unsigned short sk[64 * P];   // [s][d]
    __shared__ unsigned short sv[64 * P];   // [d][s]
    const int tid = threadIdx.x, wave = tid >> 6, lane = tid & 63;
    const int l15 = lane & 15, l4 = lane >> 4;
    const int bid = blockIdx.x;
    const int qtt = (bid < 512) ? (31 - (bid >> 5)) : ((bid - 512) >> 5);
    const int bh = bid & 31;
    const int nb = bh >> 4, hh = bh & 15;
    const int q0 = qtt << 6;
    const size_t base = (size_t)bh << 17;

    // Q fragments (B-operand: n=l15 -> q row, k=l4*8..+7 -> d), once per block
    bf16x8 qf[2];
    #pragma unroll
    for (int ks = 0; ks < 2; ++ks)
        qf[ks] = *(const bf16x8*)
            &q[base + (size_t)(q0 + wave * 16 + l15) * 64 + ks * 32 + l4 * 8];

    float l_sum = 0.f;       // partial softmax denom for q=l15 (this lane's quarter)
    f32x4 acc[4] = {};       // O^T: [d = ds*16 + l4*4 + r][q = l15]

    const int nst = qtt + 1;
    for (int st = 0; st < nst; ++st) {
        const int s0 = st << 6;
        for (int vv = tid; vv < 512; vv += 256) {
            int row = vv >> 3, col = (vv & 7) << 3;
            *(uint4*)&sk[row * P + col] =
                *(const uint4*)&k[base + (size_t)((s0 + row) << 6) + col];
            *(uint4*)&sv[row * P + col] =
                *(const uint4*)&vt[(size_t)((hh << 6) + row) * 4096 + (nb << 11) + s0 + col];
        }
        __syncthreads();

        // S^T = K Q^T in log2 domain: D[s][q], s covered by 4 ns-frags
        f32x4 s_acc[4] = {};
        #pragma unroll
        for (int ks = 0; ks < 2; ++ks)
            #pragma unroll
            for (int ns = 0; ns < 4; ++ns) {
                bf16x8 kf = *(const bf16x8*)&sk[(ns * 16 + l15) * P + ks * 32 + l4 * 8];
                s_acc[ns] = MFMA_BF16(kf, qf[ks], s_acc[ns], 0, 0, 0);
            }

        // causal mask on diagonal step: s_local > q_local (uniform branch)
        if (st == qtt) {
            const int ql = wave * 16 + l15;
            #pragma unroll
            for (int ns = 0; ns < 4; ++ns) {
                #pragma unroll
                for (int r = 0; r < 4; ++r)
                    if (ns * 16 + l4 * 4 + r > ql) s_acc[ns][r] = -1e30f;
            }
        }

        // P^T = exp2(S^T) in registers; accumulate this lane's quarter of denom
        float pe[4][4];
        #pragma unroll
        for (int ns = 0; ns < 4; ++ns) {
            #pragma unroll
            for (int r = 0; r < 4; ++r) pe[ns][r] = exp2f(s_acc[ns][r]);
            l_sum += (pe[ns][0] + pe[ns][1]) + (pe[ns][2] + pe[ns][3]);
        }

        // O^T += V^T P^T: B-frag = pe registers (slot j <-> sigma), A-frag from sv
        #pragma unroll
        for (int ks = 0; ks < 2; ++ks) {
            uint4 pw;
            pw.x = pk2t(pe[2 * ks][0], pe[2 * ks][1]);
            pw.y = pk2t(pe[2 * ks][2], pe[2 * ks][3]);
            pw.z = pk2t(pe[2 * ks + 1][0], pe[2 * ks + 1][1]);
            pw.w = pk2t(pe[2 * ks + 1][2], pe[2 * ks + 1][3]);
            bf16x8 pf = *(bf16x8*)&pw;
            #pragma unroll
            for (int ds = 0; ds < 4; ++ds) {
                const unsigned short* vrow = &sv[(ds * 16 + l15) * P + ks * 32 + l4 * 4];
                bf16x4 lo = *(const bf16x4*)vrow;          // sigma j=0..3
                bf16x4 hi = *(const bf16x4*)(vrow + 16);   // sigma j=4..7
                bf16x8 vf = __builtin_shufflevector(lo, hi, 0, 1, 2, 3, 4, 5, 6, 7);
                acc[ds] = MFMA_BF16(vf, pf, acc[ds], 0, 0, 0);
            }
        }
        __syncthreads();  // before next tile's staging overwrites sk/sv
    }

    // softmax denom for q=l15: reduce across the 4 l4 groups (lanes l15+16*l4)
    l_sum += __shfl_xor(l_sum, 16);
    l_sum += __shfl_xor(l_sum, 32);
    const float rl = __builtin_amdgcn_rcpf(l_sum);

    // y[t = nb*2048 + q0 + wave*16 + l15][hh*64 + ds*16 + l4*4 + r], 4 d per b64 store
    const size_t rowbase =
        ((size_t)((nb << 11) + q0 + wave * 16 + l15) << 10) + (hh << 6) + l4 * 4;
    #pragma unroll
    for (int ds = 0; ds < 4; ++ds) {
        uint2 o;
        o.x = pk2(acc[ds][0] * rl, acc[ds][1] * rl);
        o.y = pk2(acc[ds][2] * rl, acc[ds][3] * rl);
        *(uint2*)&y[rowbase + ds * 16] = o;
    }
}

extern "C" void kernel_launch(void* const* d_in, const int* in_sizes, int n_in,
                              void* d_out, int out_size, void* d_ws, size_t ws_size,
                              hipStream_t stream) {
    const float* x  = (const float*)d_in[0];
    const float* wq = (const float*)d_in[1];
    const float* wk = (const float*)d_in[2];
    const float* wv = (const float*)d_in[3];
    const float* wo = (const float*)d_in[4];
    float* out = (float*)d_out;

    const size_t M1 = 1u << 20;
    unsigned short* x16  = (unsigned short*)d_ws;          // 4M
    unsigned short* wq16 = x16 + 4 * M1;                   // 1M
    unsigned short* wk16 = wq16 + M1;
    unsigned short* wv16 = wk16 + M1;
    unsigned short* wot  = wv16 + M1;                      // 1M
    unsigned short* qbuf = wot + M1;                       // 4M [B,H,T,64]
    unsigned short* kbuf = qbuf + 4 * M1;                  // 4M
    unsigned short* vtb  = kbuf + 4 * M1;                  // 4M [1024][4096]
    unsigned short* ybuf = vtb + 4 * M1;                   // 4M [4096][1024]

    dim3 blk(256);
    prep<<<3840, blk, 0, stream>>>(x, wq, wk, wv, wo, x16, wq16, wk16, wv16, wot);
    proj<<<768, blk, 0, stream>>>(x16, wq16, wk16, wv16, qbuf, kbuf, vtb);
    attn<<<1024, blk, 0, stream>>>(qbuf, kbuf, vtb, ybuf);
    outp<<<512, blk, 0, stream>>>(ybuf, wot, out);
}

// Round 10
// 193.076 us; speedup vs baseline: 1.1733x; 1.0896x over previous
//
#include <hip/hip_runtime.h>

// B=2, T=2048, C=1024, H=16, DQK=DV=64. Inputs fp32, output fp32, bf16 MFMA inside.

typedef short bf16x4 __attribute__((ext_vector_type(4)));
typedef short bf16x8 __attribute__((ext_vector_type(8)));
typedef float f32x4 __attribute__((ext_vector_type(4)));

#define MFMA_BF16 __builtin_amdgcn_mfma_f32_16x16x32_bf16

// log2(e)/8: Q pre-scale so softmax runs in base-2 domain (exp2 = bare v_exp_f32)
#define QSCALE 0.18033688011112042f

__device__ __forceinline__ unsigned short f2bf(float f) {
    union { float f; unsigned u; } un; un.f = f;
    unsigned r = un.u + 0x7fffu + ((un.u >> 16) & 1u);  // RNE
    return (unsigned short)(r >> 16);
}
__device__ __forceinline__ unsigned pk2(float a, float b) {
    return (unsigned)f2bf(a) | ((unsigned)f2bf(b) << 16);
}
// truncating pack of two floats into packed bf16x2
__device__ __forceinline__ unsigned pk2t(float a, float b) {
    union { float f; unsigned u; } ua, ub; ua.f = a; ub.f = b;
    return (ua.u >> 16) | (ub.u & 0xffff0000u);
}
__device__ __forceinline__ void gload16(const void* g, void* l) {
    __builtin_amdgcn_global_load_lds(
        (const __attribute__((address_space(1))) unsigned int*)g,
        (__attribute__((address_space(3))) unsigned int*)l, 16, 0, 0);
}

// ---------- fused prep: x/wq/wk/wv fp32->bf16, wo fp32->bf16 transposed ----------
__global__ __launch_bounds__(256) void prep(
    const float* __restrict__ x, const float* __restrict__ wq,
    const float* __restrict__ wk, const float* __restrict__ wv,
    const float* __restrict__ wo,
    unsigned short* __restrict__ x16, unsigned short* __restrict__ wq16,
    unsigned short* __restrict__ wk16, unsigned short* __restrict__ wv16,
    unsigned short* __restrict__ wot)
{
    const int bid = blockIdx.x;
    if (bid < 3584) {
        const float* s; unsigned short* d; int off;
        if (bid < 2048)      { s = x;  d = x16;  off = bid * 2048; }
        else if (bid < 2560) { s = wq; d = wq16; off = (bid - 2048) * 2048; }
        else if (bid < 3072) { s = wk; d = wk16; off = (bid - 2560) * 2048; }
        else                 { s = wv; d = wv16; off = (bid - 3072) * 2048; }
        int i = off + threadIdx.x * 8;
        float4 f0 = *(const float4*)&s[i], f1 = *(const float4*)&s[i + 4];
        uint4 o;
        o.x = pk2(f0.x, f0.y); o.y = pk2(f0.z, f0.w);
        o.z = pk2(f1.x, f1.y); o.w = pk2(f1.z, f1.w);
        *(uint4*)&d[i] = o;
    } else {
        // wo [K=1024][N=1024] -> wot [N][K] bf16
        __shared__ unsigned short t[64 * 72];
        const int b2 = bid - 3584;
        const int k0 = (b2 & 15) << 6, n0 = (b2 >> 4) << 6;
        const int r = threadIdx.x >> 2, cg = (threadIdx.x & 3) << 4;
        const float* src = &wo[(k0 + r) * 1024 + n0 + cg];
        #pragma unroll
        for (int j = 0; j < 16; j += 4) {
            float4 f = *(const float4*)&src[j];
            t[(cg + j + 0) * 72 + r] = f2bf(f.x);
            t[(cg + j + 1) * 72 + r] = f2bf(f.y);
            t[(cg + j + 2) * 72 + r] = f2bf(f.z);
            t[(cg + j + 3) * 72 + r] = f2bf(f.w);
        }
        __syncthreads();
        unsigned short* dst = &wot[(n0 + r) * 1024 + k0 + cg];
        unsigned short* tr = &t[r * 72 + cg];
        unsigned v[16];
        #pragma unroll
        for (int j = 0; j < 16; ++j) v[j] = tr[j];
        uint4 o0, o1;
        o0.x = v[0] | (v[1] << 16);   o0.y = v[2] | (v[3] << 16);
        o0.z = v[4] | (v[5] << 16);   o0.w = v[6] | (v[7] << 16);
        o1.x = v[8] | (v[9] << 16);   o1.y = v[10] | (v[11] << 16);
        o1.z = v[12] | (v[13] << 16); o1.w = v[14] | (v[15] << 16);
        *(uint4*)&dst[0] = o0;
        *(uint4*)&dst[8] = o1;
    }
}

// ---------- shared 128x128 bf16 GEMM tile body, K=1024, lda=ldb=1024 ----------
__device__ __forceinline__ void gemm_body(
    const unsigned short* __restrict__ A, const unsigned short* __restrict__ Bm,
    void* __restrict__ C, int m0, int n0, int mode, int ldc, float sc)
{
    __shared__ unsigned short sa[128 * 64];
    __shared__ unsigned short sb[128 * 64];
    const int tid = threadIdx.x, wave = tid >> 6, lane = tid & 63;
    const int l15 = lane & 15, l4 = lane >> 4;
    const int wm = (wave >> 1) << 6, wn = (wave & 1) << 6;
    const int lrow = lane >> 3, lcb = (lane & 7) << 3;

    f32x4 acc[4][4] = {};

    for (int k0 = 0; k0 < 1024; k0 += 64) {
        #pragma unroll
        for (int i = 0; i < 4; ++i) {
            int rbase = i * 32 + wave * 8;
            gload16(&A[(size_t)(m0 + rbase + lrow) * 1024 + k0 + lcb], &sa[rbase * 64]);
            gload16(&Bm[(size_t)(n0 + rbase + lrow) * 1024 + k0 + lcb], &sb[rbase * 64]);
        }
        __syncthreads();
        #pragma unroll
        for (int ks = 0; ks < 2; ++ks) {
            bf16x8 af[4], bf[4];
            #pragma unroll
            for (int i = 0; i < 4; ++i)
                af[i] = *(const bf16x8*)&sa[(wm + i * 16 + l15) * 64 + ks * 32 + l4 * 8];
            #pragma unroll
            for (int j = 0; j < 4; ++j)
                bf[j] = *(const bf16x8*)&sb[(wn + j * 16 + l15) * 64 + ks * 32 + l4 * 8];
            #pragma unroll
            for (int i = 0; i < 4; ++i)
                #pragma unroll
                for (int j = 0; j < 4; ++j)
                    acc[i][j] = MFMA_BF16(af[i], bf[j], acc[i][j], 0, 0, 0);
        }
        __syncthreads();
    }

    #pragma unroll
    for (int i = 0; i < 4; ++i)
        #pragma unroll
        for (int j = 0; j < 4; ++j)
            #pragma unroll
            for (int r = 0; r < 4; ++r) {
                int row = m0 + wm + i * 16 + l4 * 4 + r;
                int col = n0 + wn + j * 16 + l15;
                float val = acc[i][j][r];
                if (mode == 0) {
                    int nb = row >> 11, t = row & 2047;
                    int hh = col >> 6, dd = col & 63;
                    ((unsigned short*)C)[(((nb << 4) + hh) * 2048 + t) * 64 + dd] =
                        f2bf(val * sc);
                } else if (mode == 1) {
                    ((float*)C)[(size_t)row * ldc + col] = val;
                } else {
                    ((unsigned short*)C)[(size_t)row * ldc + col] = f2bf(val);
                }
            }
}

// grid 768: [0,512) QK fused | [512,768) V^T = Wv @ X^T
__global__ __launch_bounds__(256) void proj(
    const unsigned short* __restrict__ x16,
    const unsigned short* __restrict__ wq16,
    const unsigned short* __restrict__ wk16,
    const unsigned short* __restrict__ wv16,
    unsigned short* __restrict__ qbuf,
    unsigned short* __restrict__ kbuf,
    unsigned short* __restrict__ vtb)
{
    const int bid = blockIdx.x;
    if (bid < 512) {
        int m0 = (bid & 31) << 7;
        int n0g = (bid >> 5) << 7;
        if (n0g < 1024)
            gemm_body(x16, wq16, qbuf, m0, n0g, 0, 0, QSCALE);
        else
            gemm_body(x16, wk16, kbuf, m0, n0g - 1024, 0, 0, 1.0f);
    } else {
        int v = bid - 512;
        gemm_body(wv16, x16, vtb, (v & 7) << 7, (v >> 3) << 7, 2, 4096, 1.0f);
    }
}

// ---------- out = Y @ Wo^T(stored [N][K]): 64x64 tiles, 1024 blocks (4/CU) ----------
// R7's 64x128 (512 blocks) was grid-limited to 2 blocks/CU; K=1024 short loops
// need cross-block overlap (same lesson as attn R7->R8).
__global__ __launch_bounds__(256) void outp(
    const unsigned short* __restrict__ ybuf,
    const unsigned short* __restrict__ wot,
    float* __restrict__ out)
{
    __shared__ unsigned short sa[64 * 64];
    __shared__ unsigned short sb[64 * 64];
    const int tid = threadIdx.x, wave = tid >> 6, lane = tid & 63;
    const int l15 = lane & 15, l4 = lane >> 4;
    const int bid = blockIdx.x;
    const int m0 = (bid & 63) << 6, n0 = (bid >> 6) << 6;
    const int lrow = lane >> 3, lcb = (lane & 7) << 3;

    f32x4 acc[4] = {};

    for (int k0 = 0; k0 < 1024; k0 += 64) {
        #pragma unroll
        for (int i = 0; i < 2; ++i) {
            int rbase = i * 32 + wave * 8;
            gload16(&ybuf[(size_t)(m0 + rbase + lrow) * 1024 + k0 + lcb], &sa[rbase * 64]);
            gload16(&wot[(size_t)(n0 + rbase + lrow) * 1024 + k0 + lcb], &sb[rbase * 64]);
        }
        __syncthreads();
        #pragma unroll
        for (int ks = 0; ks < 2; ++ks) {
            bf16x8 af = *(const bf16x8*)&sa[(wave * 16 + l15) * 64 + ks * 32 + l4 * 8];
            #pragma unroll
            for (int j = 0; j < 4; ++j) {
                bf16x8 bf = *(const bf16x8*)&sb[(j * 16 + l15) * 64 + ks * 32 + l4 * 8];
                acc[j] = MFMA_BF16(af, bf, acc[j], 0, 0, 0);
            }
        }
        __syncthreads();
    }

    #pragma unroll
    for (int j = 0; j < 4; ++j)
        #pragma unroll
        for (int r = 0; r < 4; ++r) {
            int row = m0 + wave * 16 + l4 * 4 + r;
            int col = n0 + j * 16 + l15;
            out[(size_t)row * 1024 + col] = acc[j][r];
        }
}

// ---------- flash causal attention: S^T form + software-pipelined staging ----------
// R9 analysis: serial chain barrier->staging-drain(~300cyc L2)->MFMA->exp2->PV->barrier
// is the binding constraint at 4 blocks/CU. Fix: double-buffer sk/sv; issue tile
// st+1's global loads at loop top (registers), compute on buf[st&1], ds_write the
// held registers after compute, ONE barrier per step. Load latency overlaps compute.
// S^T = K Q^T; exp2(s_acc) registers are the PV B-frag via sigma (R9, verified).
// 64 q-rows/block, 1024 blocks (4/CU); balanced causal pairing.
__global__ __launch_bounds__(256) void attn(
    const unsigned short* __restrict__ q,
    const unsigned short* __restrict__ k,
    const unsigned short* __restrict__ vt,
    unsigned short* __restrict__ y)
{
    constexpr int P = 72;
    __shared__ unsigned short sk[2][64 * P];   // [s][d]
    __shared__ unsigned short sv[2][64 * P];   // [d][s]
    const int tid = threadIdx.x, wave = tid >> 6, lane = tid & 63;
    const int l15 = lane & 15, l4 = lane >> 4;
    const int bid = blockIdx.x;
    const int qtt = (bid < 512) ? (31 - (bid >> 5)) : ((bid - 512) >> 5);
    const int bh = bid & 31;
    const int nb = bh >> 4, hh = bh & 15;
    const int q0 = qtt << 6;
    const size_t base = (size_t)bh << 17;

    // per-thread staging coordinates: rows r0, r0+32; 16B column chunk c0
    const int r0 = tid >> 3, c0 = (tid & 7) << 3;
    const unsigned short* kg = &k[base + ((size_t)r0 << 6) + c0];            // + s0*64
    const unsigned short* vg = &vt[(size_t)((hh << 6) + r0) * 4096 + (nb << 11) + c0]; // + s0
    const int lk0 = r0 * P + c0, lk1 = (r0 + 32) * P + c0;

    // Q fragments (B-operand: n=l15 -> q row, k=l4*8..+7 -> d), once per block
    bf16x8 qf[2];
    #pragma unroll
    for (int ks = 0; ks < 2; ++ks)
        qf[ks] = *(const bf16x8*)
            &q[base + (size_t)(q0 + wave * 16 + l15) * 64 + ks * 32 + l4 * 8];

    float l_sum = 0.f;       // partial softmax denom for q=l15 (this lane's quarter)
    f32x4 acc[4] = {};       // O^T: [d = ds*16 + l4*4 + r][q = l15]

    const int nst = qtt + 1;

    // prologue: stage tile 0
    {
        uint4 ka = *(const uint4*)(kg);
        uint4 kb = *(const uint4*)(kg + (32 << 6));
        uint4 va = *(const uint4*)(vg);
        uint4 vb = *(const uint4*)(vg + 32 * 4096);
        *(uint4*)&sk[0][lk0] = ka;  *(uint4*)&sk[0][lk1] = kb;
        *(uint4*)&sv[0][lk0] = va;  *(uint4*)&sv[0][lk1] = vb;
    }
    __syncthreads();

    for (int st = 0; st < nst; ++st) {
        const int cur = st & 1;
        const bool more = (st + 1) < nst;
        uint4 ka, kb, va, vb;
        if (more) {
            const int s1 = (st + 1) << 6;
            ka = *(const uint4*)(kg + ((size_t)s1 << 6));
            kb = *(const uint4*)(kg + ((size_t)(s1 + 32) << 6));
            va = *(const uint4*)(vg + s1);
            vb = *(const uint4*)(vg + 32 * 4096 + s1);
        }

        // S^T = K Q^T in log2 domain: D[s][q]
        f32x4 s_acc[4] = {};
        #pragma unroll
        for (int ks = 0; ks < 2; ++ks)
            #pragma unroll
            for (int ns = 0; ns < 4; ++ns) {
                bf16x8 kf = *(const bf16x8*)&sk[cur][(ns * 16 + l15) * P + ks * 32 + l4 * 8];
                s_acc[ns] = MFMA_BF16(kf, qf[ks], s_acc[ns], 0, 0, 0);
            }

        // causal mask on diagonal step: s_local > q_local (uniform branch)
        if (st == qtt) {
            const int ql = wave * 16 + l15;
            #pragma unroll
            for (int ns = 0; ns < 4; ++ns) {
                #pragma unroll
                for (int r = 0; r < 4; ++r)
                    if (ns * 16 + l4 * 4 + r > ql) s_acc[ns][r] = -1e30f;
            }
        }

        // P^T = exp2(S^T) in registers; accumulate this lane's quarter of denom
        float pe[4][4];
        #pragma unroll
        for (int ns = 0; ns < 4; ++ns) {
            #pragma unroll
            for (int r = 0; r < 4; ++r) pe[ns][r] = exp2f(s_acc[ns][r]);
            l_sum += (pe[ns][0] + pe[ns][1]) + (pe[ns][2] + pe[ns][3]);
        }

        // O^T += V^T P^T: B-frag = pe registers (slot j <-> sigma), A-frag from sv
        #pragma unroll
        for (int ks = 0; ks < 2; ++ks) {
            uint4 pw;
            pw.x = pk2t(pe[2 * ks][0], pe[2 * ks][1]);
            pw.y = pk2t(pe[2 * ks][2], pe[2 * ks][3]);
            pw.z = pk2t(pe[2 * ks + 1][0], pe[2 * ks + 1][1]);
            pw.w = pk2t(pe[2 * ks + 1][2], pe[2 * ks + 1][3]);
            bf16x8 pf = *(bf16x8*)&pw;
            #pragma unroll
            for (int ds = 0; ds < 4; ++ds) {
                const unsigned short* vrow =
                    &sv[cur][(ds * 16 + l15) * P + ks * 32 + l4 * 4];
                bf16x4 lo = *(const bf16x4*)vrow;          // sigma j=0..3
                bf16x4 hi = *(const bf16x4*)(vrow + 16);   // sigma j=4..7
                bf16x8 vf = __builtin_shufflevector(lo, hi, 0, 1, 2, 3, 4, 5, 6, 7);
                acc[ds] = MFMA_BF16(vf, pf, acc[ds], 0, 0, 0);
            }
        }

        // write the prefetched tile into the other buffer (after compute: load
        // latency was hidden behind the MFMA/exp2 work above)
        if (more) {
            const int nxt = 1 - cur;
            *(uint4*)&sk[nxt][lk0] = ka;  *(uint4*)&sk[nxt][lk1] = kb;
            *(uint4*)&sv[nxt][lk0] = va;  *(uint4*)&sv[nxt][lk1] = vb;
        }
        __syncthreads();
    }

    // softmax denom for q=l15: reduce across the 4 l4 groups
    l_sum += __shfl_xor(l_sum, 16);
    l_sum += __shfl_xor(l_sum, 32);
    const float rl = __builtin_amdgcn_rcpf(l_sum);

    // y[t][hh*64 + ds*16 + l4*4 + r], 4 d per b64 store
    const size_t rowbase =
        ((size_t)((nb << 11) + q0 + wave * 16 + l15) << 10) + (hh << 6) + l4 * 4;
    #pragma unroll
    for (int ds = 0; ds < 4; ++ds) {
        uint2 o;
        o.x = pk2(acc[ds][0] * rl, acc[ds][1] * rl);
        o.y = pk2(acc[ds][2] * rl, acc[ds][3] * rl);
        *(uint2*)&y[rowbase + ds * 16] = o;
    }
}

extern "C" void kernel_launch(void* const* d_in, const int* in_sizes, int n_in,
                              void* d_out, int out_size, void* d_ws, size_t ws_size,
                              hipStream_t stream) {
    const float* x  = (const float*)d_in[0];
    const float* wq = (const float*)d_in[1];
    const float* wk = (const float*)d_in[2];
    const float* wv = (const float*)d_in[3];
    const float* wo = (const float*)d_in[4];
    float* out = (float*)d_out;

    const size_t M1 = 1u << 20;
    unsigned short* x16  = (unsigned short*)d_ws;          // 4M
    unsigned short* wq16 = x16 + 4 * M1;                   // 1M
    unsigned short* wk16 = wq16 + M1;
    unsigned short* wv16 = wk16 + M1;
    unsigned short* wot  = wv16 + M1;                      // 1M
    unsigned short* qbuf = wot + M1;                       // 4M [B,H,T,64]
    unsigned short* kbuf = qbuf + 4 * M1;                  // 4M
    unsigned short* vtb  = kbuf + 4 * M1;                  // 4M [1024][4096]
    unsigned short* ybuf = vtb + 4 * M1;                   // 4M [4096][1024]

    dim3 blk(256);
    prep<<<3840, blk, 0, stream>>>(x, wq, wk, wv, wo, x16, wq16, wk16, wv16, wot);
    proj<<<768, blk, 0, stream>>>(x16, wq16, wk16, wv16, qbuf, kbuf, vtb);
    attn<<<1024, blk, 0, stream>>>(qbuf, kbuf, vtb, ybuf);
    outp<<<1024, blk, 0, stream>>>(ybuf, wot, out);
}